// Round 14
// baseline (186.096 us; speedup 1.0000x reference)
//
#include <hip/hip_runtime.h>
#include <hip/hip_bf16.h>

typedef short short8 __attribute__((ext_vector_type(8)));
typedef short short4v __attribute__((ext_vector_type(4)));
typedef float f32x4 __attribute__((ext_vector_type(4)));

constexpr int BB = 8192;   // batch
constexpr int LL = 50;     // seq len
constexpr int DE = 128;    // emb dim
constexpr int DD = 392;    // total input dim
constexpr int HH1 = 256;
constexpr int HH2 = 128;

__device__ __forceinline__ short f2b(float x) {
    __hip_bfloat16 h = __float2bfloat16(x);   // RNE
    return __builtin_bit_cast(short, h);
}
__device__ __forceinline__ float b2f(short v) {
    unsigned u = ((unsigned)(unsigned short)v) << 16;
    return __builtin_bit_cast(float, u);
}

// ---------------------------------------------------------------------------
// ONE prep kernel, segmented by blockIdx (R11/R13)
// ---------------------------------------------------------------------------
constexpr int S0 = 3 * 392 * 392;        // 460992
constexpr int S1 = 4 * 392 * 256;        // 401408
constexpr int S2 = (50001 * 128) / 4;    // 1600032 (4 elems each)
constexpr int NB_TRANS = 9619;           // ceil((S0+S1+S2)/256)
constexpr int QC0 = 36 + NB_TRANS;       // 9655
constexpr int NB_PREP = QC0 + 2048;      // 11703

__global__ __launch_bounds__(256) void prep_all(
    const float* __restrict__ w1,
    const float* __restrict__ w2, const float* __restrict__ b2,
    const float* __restrict__ head_w, const float* __restrict__ att_b1,
    const float* __restrict__ cross_W, const float* __restrict__ exp_w1,
    const float* __restrict__ emb_movie, const int* __restrict__ movieId,
    float* __restrict__ WkpFf, float* __restrict__ hw2, float* __restrict__ hc,
    short* __restrict__ WTc, short* __restrict__ WT1, short* __restrict__ embB,
    float* __restrict__ qcAll)
{
    __shared__ float sh[4][128];
    const int blk = blockIdx.x, t = threadIdx.x;

    if (blk < 32) {
        int o = blk * 256 + t;              // 8192
        int e = o & 7, lane = (o >> 3) & 63, nt = (o >> 9) & 3, kt = o >> 11;
        int k = (kt << 5) + ((lane >> 4) << 3) + e;
        int h = (nt << 4) + (lane & 15);
        int base = (o >> 3) << 4;
        WkpFf[base + e]     = w1[(128 + k) * 64 + h] - w1[(256 + k) * 64 + h];
        WkpFf[base + 8 + e] = w1[(384 + k) * 64 + h];
    } else if (blk < 36) {
        const int e = blk - 32;
        float* hw = &sh[0][0];
        hw[t] = head_w[t];
        __syncthreads();
        const float* row = &w2[((long)e * HH1 + t) * HH2];
        float s0 = 0.f, s1 = 0.f;
        #pragma unroll 8
        for (int o = 0; o < 128; o += 4) {
            float4 v = *reinterpret_cast<const float4*>(&row[o]);
            s0 += v.x * hw[o] + v.y * hw[o + 1] + v.z * hw[o + 2] + v.w * hw[o + 3];
            s1 += v.x * hw[128 + o] + v.y * hw[129 + o] + v.z * hw[130 + o] + v.w * hw[131 + o];
        }
        hw2[(((e << 8) + t) << 1) + 0] = s0;
        hw2[(((e << 8) + t) << 1) + 1] = s1;
        if (t < 2) {
            float s = 0.f;
            for (int o = 0; o < 128; ++o) s += b2[e * 128 + o] * hw[t * 128 + o];
            hc[e * 2 + t] = s;
        }
    } else if (blk < QC0) {
        int idx = (blk - 36) * 256 + t;
        if (idx < S0) {
            int z = idx / (392 * 392), rr = idx - z * 392 * 392;
            int c = rr / 392, r = rr - c * 392;
            WTc[idx] = f2b(cross_W[(long)z * 153664 + r * 392 + c]);
        } else if (idx < S0 + S1) {
            int j = idx - S0;
            int z = j / 100352, rr = j - z * 100352;
            int c = rr / 392, r = rr - c * 392;
            WT1[j] = f2b(exp_w1[(long)z * 100352 + r * 256 + c]);
        } else if (idx < S0 + S1 + S2) {
            long j = (long)(idx - S0 - S1) << 2;
            float4 v = *reinterpret_cast<const float4*>(&emb_movie[j]);
            short4v o;
            o[0] = f2b(v.x); o[1] = f2b(v.y); o[2] = f2b(v.z); o[3] = f2b(v.w);
            *reinterpret_cast<short4v*>(&embB[j]) = o;
        }
    } else {
        // qcAll: 4 rows/block, one wave per row, lane = h
        const int w = t >> 6, lane = t & 63;
        const int b = (blk - QC0) * 4 + w;
        if (lane < 32)
            *reinterpret_cast<float4*>(&sh[w][lane << 2]) =
                *reinterpret_cast<const float4*>(
                    &emb_movie[(long)movieId[b] * DE + (lane << 2)]);
        __syncthreads();
        float s = att_b1[lane];
        #pragma unroll 8
        for (int d = 0; d < 128; ++d)
            s = fmaf(sh[w][d], w1[d * 64 + lane] + w1[16384 + d * 64 + lane], s);
        qcAll[((long)b << 6) + lane] = s;
    }
}

// ---------------------------------------------------------------------------
// K1: DIN attention (R8/R13 structure, frozen) — LDS trimmed to exactly 20480B
// (stats aliased into probs[60..61]) for 8 blocks/CU.
// ---------------------------------------------------------------------------
__global__ __launch_bounds__(256, 8) void attn_kernel(
    const int* __restrict__ userId, const int* __restrict__ movieId,
    const int* __restrict__ seq, const float* __restrict__ dense,
    const float* __restrict__ emb_user, const float* __restrict__ emb_movie,
    const short* __restrict__ embB,
    const float* __restrict__ qcAll, const float* __restrict__ WkpFf,
    const float* __restrict__ att_w2, const float* __restrict__ att_b2,
    const float* __restrict__ in_gamma, const float* __restrict__ in_beta,
    float* __restrict__ x0f, short* __restrict__ x0b)
{
    __shared__ short hist[64 * 128];   // 16384 B
    __shared__ float qs[128];          //   512 B
    __shared__ int   seq_s[64];        //   256 B
    __shared__ float spS[4][64];       //  1024 B
    __shared__ float probs[64];        //   256 B (60,61 reused as LN stats)
    __shared__ float ibuf[4][128];     //  2048 B  -> total 20480 B

    const int b = blockIdx.x;
    const int t = threadIdx.x;
    const int lane = t & 63;
    const int w = t >> 6;

    if (t < 128) qs[t] = emb_movie[(long)movieId[b] * DE + t];
    if (t < 64)  seq_s[t] = (t < LL) ? seq[b * LL + t] : 0;
    __syncthreads();   // A

    #pragma unroll
    for (int i = 0; i < 4; ++i) {
        const int idx = t + (i << 8);
        const int l = idx >> 4, c = idx & 15;
        short8 hv = *reinterpret_cast<const short8*>(&embB[(long)seq_s[l] * DE + (c << 3)]);
        const int byte = (l << 8) + ((c << 4) ^ ((l & 7) << 4));
        *reinterpret_cast<short8*>(reinterpret_cast<char*>(hist) + byte) = hv;
    }

    const int col = (w << 4) + (lane & 15);
    float ue = (t < 128) ? emb_user[(long)userId[b] * DE + t] : 0.f;
    float dv = (t >= 128 && t < 136) ? dense[b * 8 + (t - 128)] : 0.f;
    const float qc  = qcAll[((long)b << 6) + col];
    const float w2v = att_w2[col];

    short8 bfrag[4];
    #pragma unroll
    for (int kt = 0; kt < 4; ++kt) {
        const float* wkp = &WkpFf[((((kt << 2) + w) << 6) | lane) << 4];
        const int kq = (kt << 5) + ((lane >> 4) << 3);
        #pragma unroll
        for (int j = 0; j < 8; ++j)
            bfrag[kt][j] = f2b(fmaf(qs[kq + j], wkp[8 + j], wkp[j]));
    }
    __syncthreads();   // B

    #pragma unroll
    for (int mt = 0; mt < 4; ++mt) {
        f32x4 acc = {0.f, 0.f, 0.f, 0.f};
        const int row = (mt << 4) + (lane & 15);
        const int rbase = row << 8;
        const int swz = (row & 7) << 4;
        #pragma unroll
        for (int kt = 0; kt < 4; ++kt) {
            const int kbyte = (kt << 6) + ((lane >> 4) << 4);
            short8 a = *reinterpret_cast<const short8*>(
                reinterpret_cast<char*>(hist) + rbase + (kbyte ^ swz));
            acc = __builtin_amdgcn_mfma_f32_16x16x32_bf16(a, bfrag[kt], acc, 0, 0, 0);
        }
        #pragma unroll
        for (int r = 0; r < 4; ++r) {
            float v = fmaxf(acc[r] + qc, 0.f) * w2v;
            v += __shfl_xor(v, 1); v += __shfl_xor(v, 2);
            v += __shfl_xor(v, 4); v += __shfl_xor(v, 8);
            if ((lane & 15) == 0)
                spS[w][(mt << 4) + ((lane >> 4) << 2) + r] = v;
        }
    }
    __syncthreads();   // C

    if (t < 64) {
        float sc = spS[0][t] + spS[1][t] + spS[2][t] + spS[3][t] + att_b2[0];
        float s = (t < LL) ? ((seq_s[t] > 0) ? sc : -1e9f) : -INFINITY;
        float m = s;
        #pragma unroll
        for (int off = 32; off > 0; off >>= 1) m = fmaxf(m, __shfl_xor(m, off));
        float e = (t < LL) ? __expf(s - m) : 0.f;
        float sum = e;
        #pragma unroll
        for (int off = 32; off > 0; off >>= 1) sum += __shfl_xor(sum, off);
        probs[t] = (t < LL) ? (e / sum) : 0.f;
    }
    __syncthreads();   // D

    const int g  = t >> 5;
    const int d0 = (t & 31) << 2;
    float4 ps = make_float4(0.f, 0.f, 0.f, 0.f);
    #pragma unroll
    for (int i = 0; i < 8; ++i) {
        const int l = g + (i << 3);
        const int byte = (l << 8) + ((d0 << 1) ^ ((l & 7) << 4));
        short4v hv = *reinterpret_cast<const short4v*>(
            reinterpret_cast<const char*>(hist) + byte);
        const float p = probs[l];
        ps.x = fmaf(p, b2f(hv[0]), ps.x);
        ps.y = fmaf(p, b2f(hv[1]), ps.y);
        ps.z = fmaf(p, b2f(hv[2]), ps.z);
        ps.w = fmaf(p, b2f(hv[3]), ps.w);
    }
    ps.x += __shfl_xor(ps.x, 32); ps.y += __shfl_xor(ps.y, 32);
    ps.z += __shfl_xor(ps.z, 32); ps.w += __shfl_xor(ps.w, 32);
    if (lane < 32)
        *reinterpret_cast<float4*>(&ibuf[w][(lane & 31) << 2]) = ps;
    __syncthreads();   // E

    float v0 = (t < 128) ? ue : qs[t - 128];
    float v1 = 0.f;
    if (t < 128)       v1 = ibuf[0][t] + ibuf[1][t] + ibuf[2][t] + ibuf[3][t];
    else if (t < 136)  v1 = dv;

    float s2 = v0 + v1, q2 = v0 * v0 + v1 * v1;
    #pragma unroll
    for (int off = 32; off > 0; off >>= 1) {
        s2 += __shfl_xor(s2, off);
        q2 += __shfl_xor(q2, off);
    }
    if (lane == 0) { spS[0][w] = s2; spS[1][w] = q2; }
    __syncthreads();   // F
    if (t == 0) {
        float S = spS[0][0] + spS[0][1] + spS[0][2] + spS[0][3];
        float Q = spS[1][0] + spS[1][1] + spS[1][2] + spS[1][3];
        float mean = S / (float)DD;
        float var = Q / (float)DD - mean * mean;
        probs[60] = mean;                    // aliased LN stats
        probs[61] = rsqrtf(var + 1e-5f);
    }
    __syncthreads();   // G
    const float mean = probs[60], inv = probs[61];
    const long base = (long)b * DD;
    float o0 = (v0 - mean) * inv * in_gamma[t] + in_beta[t];
    x0f[base + t] = o0; x0b[base + t] = f2b(o0);
    if (t < 136) {
        float o1 = (v1 - mean) * inv * in_gamma[256 + t] + in_beta[256 + t];
        x0f[base + 256 + t] = o1; x0b[base + 256 + t] = f2b(o1);
    }
}

// ---------------------------------------------------------------------------
// bf16 MFMA GEMM 64x64 + MODE 3 expert-head epilogue (R13, unchanged)
// MODE 0: +bias ; 1: relu(+bias) ; 2: cross ; 3: relu + hw2-dot partials
// ---------------------------------------------------------------------------
template<int MODE, int WF32, int WB16, int NXB, int NZB>
__global__ __launch_bounds__(256) void bgemm(
    const short* __restrict__ A, const short* __restrict__ WT,
    const float* __restrict__ bias,
    float* __restrict__ outF, short* __restrict__ outB,
    const float* __restrict__ x0, const float* __restrict__ xin,
    int M, int N, int K, long aZ, long wZ, long bZ, long oZ)
{
    __shared__ short As[2][64 * 64];
    __shared__ short Bs[2][64 * 64];

    int id = blockIdx.x;
    const int qq = (int)gridDim.x >> 3;
    id = (id & 7) * qq + (id >> 3);
    const int mb  = id / (NXB * NZB);
    const int rem = id - mb * (NXB * NZB);
    const int z   = rem / NXB;
    const int xb  = rem - z * NXB;

    A += (long)z * aZ; WT += (long)z * wZ; bias += (long)z * bZ;
    const long oz = (long)z * oZ;

    const int t = threadIdx.x, w = t >> 6, lane = t & 63;
    const int m0 = mb * 64, n0 = xb * 64;
    const int sm = t >> 3, sk8 = (t & 7) << 3;

    f32x4 acc[4];
    #pragma unroll
    for (int i = 0; i < 4; ++i) {
        #pragma unroll
        for (int r = 0; r < 4; ++r) acc[i][r] = 0.f;
    }

    const int nsteps = (K + 63) >> 6;
    short8 avA[2], bvA[2];

    auto loadA = [&](int k0) {
        #pragma unroll
        for (int i = 0; i < 2; ++i) {
            const int r = sm + (i << 5);
            short8 zv = {0, 0, 0, 0, 0, 0, 0, 0};
            avA[i] = zv; bvA[i] = zv;
            if (k0 + sk8 < K) {
                avA[i] = *reinterpret_cast<const short8*>(&A[(long)(m0 + r) * K + k0 + sk8]);
                if (n0 + r < N)
                    bvA[i] = *reinterpret_cast<const short8*>(&WT[(long)(n0 + r) * K + k0 + sk8]);
            }
        }
    };
    auto wrA = [&](int buf) {
        #pragma unroll
        for (int i = 0; i < 2; ++i) {
            const int r = sm + (i << 5);
            const int byte = (r << 7) + ((sk8 << 1) ^ ((r & 7) << 4));
            *reinterpret_cast<short8*>(reinterpret_cast<char*>(&As[buf][0]) + byte) = avA[i];
            *reinterpret_cast<short8*>(reinterpret_cast<char*>(&Bs[buf][0]) + byte) = bvA[i];
        }
    };
    auto domfma = [&](int buf) {
        #pragma unroll
        for (int kt = 0; kt < 2; ++kt) {
            const int kbyte = (kt << 6) + ((lane >> 4) << 4);
            const int ar = (w << 4) + (lane & 15);
            short8 a = *reinterpret_cast<const short8*>(
                reinterpret_cast<char*>(&As[buf][0]) + (ar << 7) + (kbyte ^ ((ar & 7) << 4)));
            #pragma unroll
            for (int nt = 0; nt < 4; ++nt) {
                const int br = (nt << 4) + (lane & 15);
                short8 bb = *reinterpret_cast<const short8*>(
                    reinterpret_cast<char*>(&Bs[buf][0]) + (br << 7) + (kbyte ^ ((br & 7) << 4)));
                acc[nt] = __builtin_amdgcn_mfma_f32_16x16x32_bf16(a, bb, acc[nt], 0, 0, 0);
            }
        }
    };

    loadA(0);
    wrA(0);
    if (nsteps > 1) loadA(64);
    __syncthreads();

    int cur = 0;
    for (int s = 0; s + 1 < nsteps; ++s) {
        domfma(cur);
        wrA(cur ^ 1);
        if (s + 2 < nsteps) loadA((s + 2) << 6);
        __syncthreads();
        cur ^= 1;
    }
    domfma(cur);

    if (MODE == 3) {
        const int l15 = lane & 15, g = lane >> 4;
        float pe[4][2];
        #pragma unroll
        for (int r = 0; r < 4; ++r) { pe[r][0] = 0.f; pe[r][1] = 0.f; }
        #pragma unroll
        for (int nt = 0; nt < 4; ++nt) {
            const int c = n0 + (nt << 4) + l15;
            const float bv = bias[c];
            const float hw0 = x0[(((z << 8) + c) << 1) + 0];
            const float hw1 = x0[(((z << 8) + c) << 1) + 1];
            #pragma unroll
            for (int r = 0; r < 4; ++r) {
                float v = fmaxf(acc[nt][r] + bv, 0.f);
                pe[r][0] = fmaf(v, hw0, pe[r][0]);
                pe[r][1] = fmaf(v, hw1, pe[r][1]);
            }
        }
        #pragma unroll
        for (int r = 0; r < 4; ++r) {
            #pragma unroll
            for (int tt = 0; tt < 2; ++tt) {
                float v = pe[r][tt];
                v += __shfl_xor(v, 1); v += __shfl_xor(v, 2);
                v += __shfl_xor(v, 4); v += __shfl_xor(v, 8);
                pe[r][tt] = v;
            }
        }
        if (l15 == 0) {
            #pragma unroll
            for (int r = 0; r < 4; ++r) {
                const int row = m0 + (w << 4) + (g << 2) + r;
                const long o = (long)(((xb << 2) | z) * BB + row) << 1;
                outF[o + 0] = pe[r][0];
                outF[o + 1] = pe[r][1];
            }
        }
    } else {
        #pragma unroll
        for (int nt = 0; nt < 4; ++nt) {
            const int c = n0 + (nt << 4) + (lane & 15);
            if (c < N) {
                const float bv = bias[c];
                #pragma unroll
                for (int r = 0; r < 4; ++r) {
                    const int row = m0 + (w << 4) + ((lane >> 4) << 2) + r;
                    float v = acc[nt][r] + bv;
                    if (MODE == 1) v = fmaxf(v, 0.f);
                    const long o = (long)row * N + c;
                    if (MODE == 2) v = x0[o] * v + xin[o];
                    if (WF32) outF[oz + o] = v;
                    if (WB16) outB[oz + o] = f2b(v);
                }
            }
        }
    }
}

// ---------------------------------------------------------------------------
// LayerNorm over 392 (block per row) -> bf16 out + fused gate logits (glog)
// ---------------------------------------------------------------------------
__global__ __launch_bounds__(256) void ln_kernel(
    const float* __restrict__ in,
    const float* __restrict__ gamma, const float* __restrict__ beta,
    const float* __restrict__ gate_w,
    short* __restrict__ outB, float* __restrict__ glog)
{
    __shared__ float red[2][4];
    __shared__ float gred[4][8];
    __shared__ float stats[2];
    const int b = blockIdx.x, t = threadIdx.x, lane = t & 63, w = t >> 6;
    const long base = (long)b * DD;
    float v0 = in[base + t];
    float v1 = (t < 136) ? in[base + 256 + t] : 0.f;
    float s = v0 + v1, q2 = v0 * v0 + v1 * v1;
    #pragma unroll
    for (int off = 32; off > 0; off >>= 1) {
        s += __shfl_xor(s, off);
        q2 += __shfl_xor(q2, off);
    }
    if (lane == 0) { red[0][w] = s; red[1][w] = q2; }
    __syncthreads();
    if (t == 0) {
        float S = red[0][0] + red[0][1] + red[0][2] + red[0][3];
        float Q = red[1][0] + red[1][1] + red[1][2] + red[1][3];
        float mean = S / (float)DD;
        float var = Q / (float)DD - mean * mean;
        stats[0] = mean;
        stats[1] = rsqrtf(var + 1e-5f);
    }
    __syncthreads();
    const float mean = stats[0], inv = stats[1];

    float o0 = (v0 - mean) * inv * gamma[t] + beta[t];
    outB[base + t] = f2b(o0);
    float o1 = 0.f;
    if (t < 136) {
        o1 = (v1 - mean) * inv * gamma[256 + t] + beta[256 + t];
        outB[base + 256 + t] = f2b(o1);
    }

    // fused gate logits: gp[j] = sum_d xn[d] * gate_w[tt][d][e], j = tt*4+e
    float gp[8];
    {
        float4 g0 = *reinterpret_cast<const float4*>(&gate_w[t << 2]);
        float4 g1 = *reinterpret_cast<const float4*>(&gate_w[1568 + (t << 2)]);
        gp[0] = o0 * g0.x; gp[1] = o0 * g0.y; gp[2] = o0 * g0.z; gp[3] = o0 * g0.w;
        gp[4] = o0 * g1.x; gp[5] = o0 * g1.y; gp[6] = o0 * g1.z; gp[7] = o0 * g1.w;
    }
    if (t < 136) {
        const int d = 256 + t;
        float4 g0 = *reinterpret_cast<const float4*>(&gate_w[d << 2]);
        float4 g1 = *reinterpret_cast<const float4*>(&gate_w[1568 + (d << 2)]);
        gp[0] = fmaf(o1, g0.x, gp[0]); gp[1] = fmaf(o1, g0.y, gp[1]);
        gp[2] = fmaf(o1, g0.z, gp[2]); gp[3] = fmaf(o1, g0.w, gp[3]);
        gp[4] = fmaf(o1, g1.x, gp[4]); gp[5] = fmaf(o1, g1.y, gp[5]);
        gp[6] = fmaf(o1, g1.z, gp[6]); gp[7] = fmaf(o1, g1.w, gp[7]);
    }
    #pragma unroll
    for (int v = 0; v < 8; ++v) {
        #pragma unroll
        for (int off = 32; off > 0; off >>= 1) gp[v] += __shfl_xor(gp[v], off);
    }
    if (lane == 0) {
        #pragma unroll
        for (int v = 0; v < 8; ++v) gred[w][v] = gp[v];
    }
    __syncthreads();
    if (t < 8)
        glog[((long)b << 3) + t] = gred[0][t] + gred[1][t] + gred[2][t] + gred[3][t];
}

// ---------------------------------------------------------------------------
// K3: glog + edPart sums + softmax mix -> logits
// ---------------------------------------------------------------------------
__global__ __launch_bounds__(256) void final_kernel(
    const float* __restrict__ glog, const float* __restrict__ edPart,
    const float* __restrict__ hc, const float* __restrict__ gate_b,
    const float* __restrict__ head_b, float* __restrict__ out)
{
    const int t = threadIdx.x, lane = t & 63, w = t >> 6;
    const int b = blockIdx.x * 4 + w;

    float edv = 0.f, glv = 0.f;
    if (lane < 8) {
        const int tt = lane >> 2, e = lane & 3;
        #pragma unroll
        for (int nb = 0; nb < 4; ++nb)
            edv += edPart[((long)((nb << 2) | e) * BB + b) * 2 + tt];
        glv = glog[((long)b << 3) + lane] + gate_b[lane];
    }
    float edArr[8], glArr[8];
    #pragma unroll
    for (int v = 0; v < 8; ++v) {
        edArr[v] = __shfl(edv, v);
        glArr[v] = __shfl(glv, v);
    }

    if (lane == 0) {
        float res[2];
        #pragma unroll
        for (int tt = 0; tt < 2; ++tt) {
            float lv[4], m = -1e30f;
            #pragma unroll
            for (int e = 0; e < 4; ++e) {
                lv[e] = glArr[tt * 4 + e];
                m = fmaxf(m, lv[e]);
            }
            float sum = 0.f, acc = 0.f;
            #pragma unroll
            for (int e = 0; e < 4; ++e) { lv[e] = __expf(lv[e] - m); sum += lv[e]; }
            #pragma unroll
            for (int e = 0; e < 4; ++e)
                acc = fmaf(lv[e], edArr[tt * 4 + e] + hc[e * 2 + tt], acc);
            res[tt] = head_b[tt] + acc / sum;
        }
        out[b] = res[0];
        out[BB + b] = res[1];
    }
}

// ---------------------------------------------------------------------------
extern "C" void kernel_launch(void* const* d_in, const int* in_sizes, int n_in,
                              void* d_out, int out_size, void* d_ws, size_t ws_size,
                              hipStream_t stream) {
    const int*   userId    = (const int*)d_in[0];
    const int*   movieId   = (const int*)d_in[1];
    const int*   seq       = (const int*)d_in[2];
    const float* dense     = (const float*)d_in[3];
    const float* emb_user  = (const float*)d_in[4];
    const float* emb_movie = (const float*)d_in[5];
    const float* att_w1    = (const float*)d_in[6];
    const float* att_b1    = (const float*)d_in[7];
    const float* att_w2    = (const float*)d_in[8];
    const float* att_b2    = (const float*)d_in[9];
    const float* in_gamma  = (const float*)d_in[10];
    const float* in_beta   = (const float*)d_in[11];
    const float* cr_gamma  = (const float*)d_in[12];
    const float* cr_beta   = (const float*)d_in[13];
    const float* cross_W   = (const float*)d_in[14];
    const float* cross_b   = (const float*)d_in[15];
    const float* exp_w1    = (const float*)d_in[16];
    const float* exp_b1    = (const float*)d_in[17];
    const float* exp_w2    = (const float*)d_in[18];
    const float* exp_b2    = (const float*)d_in[19];
    const float* gate_w    = (const float*)d_in[20];
    const float* gate_b    = (const float*)d_in[21];
    const float* head_w    = (const float*)d_in[22];
    const float* head_b    = (const float*)d_in[23];
    float* outp = (float*)d_out;

    char* p = (char*)d_ws;
    auto alloc = [&](size_t bytes) -> char* {
        char* r = p; p += (bytes + 255) & ~(size_t)255; return r;
    };
    float* WkpFf = (float*)alloc(16384 * 4);
    float* hw2 = (float*)alloc(2048 * 4);
    float* hc  = (float*)alloc(8 * 4);
    short* WTc = (short*)alloc((size_t)3 * 392 * 392 * 2);
    short* WT1 = (short*)alloc((size_t)4 * 256 * 392 * 2);
    short* embB = (short*)alloc((size_t)50001 * 128 * 2);
    float* qcAll = (float*)alloc((size_t)BB * 64 * 4);
    float* x0f = (float*)alloc((size_t)BB * DD * 4);
    short* x0b = (short*)alloc((size_t)BB * DD * 2);
    float* xAf = (float*)alloc((size_t)BB * DD * 4);
    short* xAb = (short*)alloc((size_t)BB * DD * 2);
    float* xBf = (float*)alloc((size_t)BB * DD * 4);
    short* xBb = (short*)alloc((size_t)BB * DD * 2);
    float* xCf = (float*)alloc((size_t)BB * DD * 4);
    short* xDb = (short*)alloc((size_t)BB * DD * 2);
    float* edPart = (float*)alloc((size_t)16 * BB * 2 * 4);   // [nb*4+e][row][2]
    float* glog = (float*)alloc((size_t)BB * 8 * 4);

    prep_all<<<NB_PREP, 256, 0, stream>>>(
        att_w1, exp_w2, exp_b2, head_w, att_b1, cross_W, exp_w1,
        emb_movie, movieId, WkpFf, hw2, hc, WTc, WT1, embB, qcAll);

    attn_kernel<<<BB, 256, 0, stream>>>(userId, movieId, seq, dense,
                                        emb_user, emb_movie, embB,
                                        qcAll, WkpFf, att_w2, att_b2,
                                        in_gamma, in_beta, x0f, x0b);

    // CrossNetV2: grid = 128 m-blocks * 7 n-blocks = 896 (%8==0)
    bgemm<2, 1, 1, 7, 1><<<896, 256, 0, stream>>>(x0b, WTc, cross_b, xAf, xAb,
                                                  x0f, x0f, BB, DD, DD, 0, 0, 0, 0);
    bgemm<2, 1, 1, 7, 1><<<896, 256, 0, stream>>>(xAb, WTc + 392 * 392, cross_b + 392,
                                                  xBf, xBb, x0f, xAf, BB, DD, DD, 0, 0, 0, 0);
    bgemm<2, 1, 0, 7, 1><<<896, 256, 0, stream>>>(xBb, WTc + 2 * 392 * 392, cross_b + 784,
                                                  xCf, nullptr, x0f, xBf, BB, DD, DD, 0, 0, 0, 0);

    // LN2 + gate logits: xCf -> xDb, glog
    ln_kernel<<<BB, 256, 0, stream>>>(xCf, cr_gamma, cr_beta, gate_w, xDb, glog);

    // Experts layer 1 fused with head dot -> edPart (no h1 materialization)
    bgemm<3, 0, 0, 4, 4><<<2048, 256, 0, stream>>>(
        xDb, WT1, exp_b1, edPart, nullptr, hw2, nullptr,
        BB, HH1, DD, 0, (long)HH1 * DD, HH1, 0);

    // glog + edPart + mix -> logits [2][B]
    final_kernel<<<BB / 4, 256, 0, stream>>>(glog, edPart, hc,
                                             gate_b, head_b, outp);

    (void)in_sizes; (void)n_in; (void)out_size; (void)ws_size;
}

// Round 15
// 173.137 us; speedup vs baseline: 1.0749x; 1.0749x over previous
//
#include <hip/hip_runtime.h>
#include <hip/hip_bf16.h>

typedef short short8 __attribute__((ext_vector_type(8)));
typedef short short4v __attribute__((ext_vector_type(4)));
typedef float f32x4 __attribute__((ext_vector_type(4)));

constexpr int BB = 8192;   // batch
constexpr int LL = 50;     // seq len
constexpr int DE = 128;    // emb dim
constexpr int DD = 392;    // total input dim
constexpr int HH1 = 256;
constexpr int HH2 = 128;

__device__ __forceinline__ short f2b(float x) {
    __hip_bfloat16 h = __float2bfloat16(x);   // RNE
    return __builtin_bit_cast(short, h);
}
__device__ __forceinline__ float b2f(short v) {
    unsigned u = ((unsigned)(unsigned short)v) << 16;
    return __builtin_bit_cast(float, u);
}

// ---------------------------------------------------------------------------
// ONE prep kernel, segmented by blockIdx (R11/R13)
// ---------------------------------------------------------------------------
constexpr int S0 = 3 * 392 * 392;        // 460992
constexpr int S1 = 4 * 392 * 256;        // 401408
constexpr int S2 = (50001 * 128) / 4;    // 1600032 (4 elems each)
constexpr int NB_TRANS = 9619;           // ceil((S0+S1+S2)/256)
constexpr int QC0 = 36 + NB_TRANS;       // 9655
constexpr int NB_PREP = QC0 + 2048;      // 11703

__global__ __launch_bounds__(256) void prep_all(
    const float* __restrict__ w1,
    const float* __restrict__ w2, const float* __restrict__ b2,
    const float* __restrict__ head_w, const float* __restrict__ att_b1,
    const float* __restrict__ cross_W, const float* __restrict__ exp_w1,
    const float* __restrict__ emb_movie, const int* __restrict__ movieId,
    float* __restrict__ WkpFf, float* __restrict__ hw2, float* __restrict__ hc,
    short* __restrict__ WTc, short* __restrict__ WT1, short* __restrict__ embB,
    float* __restrict__ qcAll)
{
    __shared__ float sh[4][128];
    const int blk = blockIdx.x, t = threadIdx.x;

    if (blk < 32) {
        int o = blk * 256 + t;              // 8192
        int e = o & 7, lane = (o >> 3) & 63, nt = (o >> 9) & 3, kt = o >> 11;
        int k = (kt << 5) + ((lane >> 4) << 3) + e;
        int h = (nt << 4) + (lane & 15);
        int base = (o >> 3) << 4;
        WkpFf[base + e]     = w1[(128 + k) * 64 + h] - w1[(256 + k) * 64 + h];
        WkpFf[base + 8 + e] = w1[(384 + k) * 64 + h];
    } else if (blk < 36) {
        const int e = blk - 32;
        float* hw = &sh[0][0];
        hw[t] = head_w[t];
        __syncthreads();
        const float* row = &w2[((long)e * HH1 + t) * HH2];
        float s0 = 0.f, s1 = 0.f;
        #pragma unroll 8
        for (int o = 0; o < 128; o += 4) {
            float4 v = *reinterpret_cast<const float4*>(&row[o]);
            s0 += v.x * hw[o] + v.y * hw[o + 1] + v.z * hw[o + 2] + v.w * hw[o + 3];
            s1 += v.x * hw[128 + o] + v.y * hw[129 + o] + v.z * hw[130 + o] + v.w * hw[131 + o];
        }
        hw2[(((e << 8) + t) << 1) + 0] = s0;
        hw2[(((e << 8) + t) << 1) + 1] = s1;
        if (t < 2) {
            float s = 0.f;
            for (int o = 0; o < 128; ++o) s += b2[e * 128 + o] * hw[t * 128 + o];
            hc[e * 2 + t] = s;
        }
    } else if (blk < QC0) {
        int idx = (blk - 36) * 256 + t;
        if (idx < S0) {
            int z = idx / (392 * 392), rr = idx - z * 392 * 392;
            int c = rr / 392, r = rr - c * 392;
            WTc[idx] = f2b(cross_W[(long)z * 153664 + r * 392 + c]);
        } else if (idx < S0 + S1) {
            int j = idx - S0;
            int z = j / 100352, rr = j - z * 100352;
            int c = rr / 392, r = rr - c * 392;
            WT1[j] = f2b(exp_w1[(long)z * 100352 + r * 256 + c]);
        } else if (idx < S0 + S1 + S2) {
            long j = (long)(idx - S0 - S1) << 2;
            float4 v = *reinterpret_cast<const float4*>(&emb_movie[j]);
            short4v o;
            o[0] = f2b(v.x); o[1] = f2b(v.y); o[2] = f2b(v.z); o[3] = f2b(v.w);
            *reinterpret_cast<short4v*>(&embB[j]) = o;
        }
    } else {
        // qcAll: 4 rows/block, one wave per row, lane = h
        const int w = t >> 6, lane = t & 63;
        const int b = (blk - QC0) * 4 + w;
        if (lane < 32)
            *reinterpret_cast<float4*>(&sh[w][lane << 2]) =
                *reinterpret_cast<const float4*>(
                    &emb_movie[(long)movieId[b] * DE + (lane << 2)]);
        __syncthreads();
        float s = att_b1[lane];
        #pragma unroll 8
        for (int d = 0; d < 128; ++d)
            s = fmaf(sh[w][d], w1[d * 64 + lane] + w1[16384 + d * 64 + lane], s);
        qcAll[((long)b << 6) + lane] = s;
    }
}

// ---------------------------------------------------------------------------
// K1: DIN attention (R8/R13 structure — best measured, frozen)
// ---------------------------------------------------------------------------
__global__ __launch_bounds__(256, 8) void attn_kernel(
    const int* __restrict__ userId, const int* __restrict__ movieId,
    const int* __restrict__ seq, const float* __restrict__ dense,
    const float* __restrict__ emb_user, const float* __restrict__ emb_movie,
    const short* __restrict__ embB,
    const float* __restrict__ qcAll, const float* __restrict__ WkpFf,
    const float* __restrict__ att_w2, const float* __restrict__ att_b2,
    const float* __restrict__ in_gamma, const float* __restrict__ in_beta,
    float* __restrict__ x0f, short* __restrict__ x0b)
{
    __shared__ short hist[64 * 128];
    __shared__ float qs[128];
    __shared__ int   seq_s[64];
    __shared__ float spS[4][64];
    __shared__ float probs[64];
    __shared__ float ibuf[4][128];
    __shared__ float stats[2];

    const int b = blockIdx.x;
    const int t = threadIdx.x;
    const int lane = t & 63;
    const int w = t >> 6;

    if (t < 128) qs[t] = emb_movie[(long)movieId[b] * DE + t];
    if (t < 64)  seq_s[t] = (t < LL) ? seq[b * LL + t] : 0;
    __syncthreads();   // A

    #pragma unroll
    for (int i = 0; i < 4; ++i) {
        const int idx = t + (i << 8);
        const int l = idx >> 4, c = idx & 15;
        short8 hv = *reinterpret_cast<const short8*>(&embB[(long)seq_s[l] * DE + (c << 3)]);
        const int byte = (l << 8) + ((c << 4) ^ ((l & 7) << 4));
        *reinterpret_cast<short8*>(reinterpret_cast<char*>(hist) + byte) = hv;
    }

    const int col = (w << 4) + (lane & 15);
    float ue = (t < 128) ? emb_user[(long)userId[b] * DE + t] : 0.f;
    float dv = (t >= 128 && t < 136) ? dense[b * 8 + (t - 128)] : 0.f;
    const float qc  = qcAll[((long)b << 6) + col];
    const float w2v = att_w2[col];

    short8 bfrag[4];
    #pragma unroll
    for (int kt = 0; kt < 4; ++kt) {
        const float* wkp = &WkpFf[((((kt << 2) + w) << 6) | lane) << 4];
        const int kq = (kt << 5) + ((lane >> 4) << 3);
        #pragma unroll
        for (int j = 0; j < 8; ++j)
            bfrag[kt][j] = f2b(fmaf(qs[kq + j], wkp[8 + j], wkp[j]));
    }
    __syncthreads();   // B

    #pragma unroll
    for (int mt = 0; mt < 4; ++mt) {
        f32x4 acc = {0.f, 0.f, 0.f, 0.f};
        const int row = (mt << 4) + (lane & 15);
        const int rbase = row << 8;
        const int swz = (row & 7) << 4;
        #pragma unroll
        for (int kt = 0; kt < 4; ++kt) {
            const int kbyte = (kt << 6) + ((lane >> 4) << 4);
            short8 a = *reinterpret_cast<const short8*>(
                reinterpret_cast<char*>(hist) + rbase + (kbyte ^ swz));
            acc = __builtin_amdgcn_mfma_f32_16x16x32_bf16(a, bfrag[kt], acc, 0, 0, 0);
        }
        #pragma unroll
        for (int r = 0; r < 4; ++r) {
            float v = fmaxf(acc[r] + qc, 0.f) * w2v;
            v += __shfl_xor(v, 1); v += __shfl_xor(v, 2);
            v += __shfl_xor(v, 4); v += __shfl_xor(v, 8);
            if ((lane & 15) == 0)
                spS[w][(mt << 4) + ((lane >> 4) << 2) + r] = v;
        }
    }
    __syncthreads();   // C

    if (t < 64) {
        float sc = spS[0][t] + spS[1][t] + spS[2][t] + spS[3][t] + att_b2[0];
        float s = (t < LL) ? ((seq_s[t] > 0) ? sc : -1e9f) : -INFINITY;
        float m = s;
        #pragma unroll
        for (int off = 32; off > 0; off >>= 1) m = fmaxf(m, __shfl_xor(m, off));
        float e = (t < LL) ? __expf(s - m) : 0.f;
        float sum = e;
        #pragma unroll
        for (int off = 32; off > 0; off >>= 1) sum += __shfl_xor(sum, off);
        probs[t] = (t < LL) ? (e / sum) : 0.f;
    }
    __syncthreads();   // D

    const int g  = t >> 5;
    const int d0 = (t & 31) << 2;
    float4 ps = make_float4(0.f, 0.f, 0.f, 0.f);
    #pragma unroll
    for (int i = 0; i < 8; ++i) {
        const int l = g + (i << 3);
        const int byte = (l << 8) + ((d0 << 1) ^ ((l & 7) << 4));
        short4v hv = *reinterpret_cast<const short4v*>(
            reinterpret_cast<const char*>(hist) + byte);
        const float p = probs[l];
        ps.x = fmaf(p, b2f(hv[0]), ps.x);
        ps.y = fmaf(p, b2f(hv[1]), ps.y);
        ps.z = fmaf(p, b2f(hv[2]), ps.z);
        ps.w = fmaf(p, b2f(hv[3]), ps.w);
    }
    ps.x += __shfl_xor(ps.x, 32); ps.y += __shfl_xor(ps.y, 32);
    ps.z += __shfl_xor(ps.z, 32); ps.w += __shfl_xor(ps.w, 32);
    if (lane < 32)
        *reinterpret_cast<float4*>(&ibuf[w][(lane & 31) << 2]) = ps;
    __syncthreads();   // E

    float v0 = (t < 128) ? ue : qs[t - 128];
    float v1 = 0.f;
    if (t < 128)       v1 = ibuf[0][t] + ibuf[1][t] + ibuf[2][t] + ibuf[3][t];
    else if (t < 136)  v1 = dv;

    float s2 = v0 + v1, q2 = v0 * v0 + v1 * v1;
    #pragma unroll
    for (int off = 32; off > 0; off >>= 1) {
        s2 += __shfl_xor(s2, off);
        q2 += __shfl_xor(q2, off);
    }
    if (lane == 0) { spS[0][w] = s2; spS[1][w] = q2; }
    __syncthreads();   // F
    if (t == 0) {
        float S = spS[0][0] + spS[0][1] + spS[0][2] + spS[0][3];
        float Q = spS[1][0] + spS[1][1] + spS[1][2] + spS[1][3];
        float mean = S / (float)DD;
        float var = Q / (float)DD - mean * mean;
        stats[0] = mean;
        stats[1] = rsqrtf(var + 1e-5f);
    }
    __syncthreads();   // G
    const float mean = stats[0], inv = stats[1];
    const long base = (long)b * DD;
    float o0 = (v0 - mean) * inv * in_gamma[t] + in_beta[t];
    x0f[base + t] = o0; x0b[base + t] = f2b(o0);
    if (t < 136) {
        float o1 = (v1 - mean) * inv * in_gamma[256 + t] + in_beta[256 + t];
        x0f[base + 256 + t] = o1; x0b[base + 256 + t] = f2b(o1);
    }
}

// ---------------------------------------------------------------------------
// bf16 MFMA GEMM 64x64 + MODE 3: expert-head epilogue (no h1 output;
// per-block partial dot vs hw2 -> edPart[nb*4+e][row][2], deterministic).
// MODE 0: +bias ; 1: relu(+bias) ; 2: cross ; 3: relu + hw2-dot partials
// ---------------------------------------------------------------------------
template<int MODE, int WF32, int WB16, int NXB, int NZB>
__global__ __launch_bounds__(256) void bgemm(
    const short* __restrict__ A, const short* __restrict__ WT,
    const float* __restrict__ bias,
    float* __restrict__ outF, short* __restrict__ outB,
    const float* __restrict__ x0, const float* __restrict__ xin,
    int M, int N, int K, long aZ, long wZ, long bZ, long oZ)
{
    __shared__ short As[2][64 * 64];
    __shared__ short Bs[2][64 * 64];

    int id = blockIdx.x;
    const int qq = (int)gridDim.x >> 3;
    id = (id & 7) * qq + (id >> 3);
    const int mb  = id / (NXB * NZB);
    const int rem = id - mb * (NXB * NZB);
    const int z   = rem / NXB;
    const int xb  = rem - z * NXB;

    A += (long)z * aZ; WT += (long)z * wZ; bias += (long)z * bZ;
    const long oz = (long)z * oZ;

    const int t = threadIdx.x, w = t >> 6, lane = t & 63;
    const int m0 = mb * 64, n0 = xb * 64;
    const int sm = t >> 3, sk8 = (t & 7) << 3;

    f32x4 acc[4];
    #pragma unroll
    for (int i = 0; i < 4; ++i) {
        #pragma unroll
        for (int r = 0; r < 4; ++r) acc[i][r] = 0.f;
    }

    const int nsteps = (K + 63) >> 6;
    short8 avA[2], bvA[2];

    auto loadA = [&](int k0) {
        #pragma unroll
        for (int i = 0; i < 2; ++i) {
            const int r = sm + (i << 5);
            short8 zv = {0, 0, 0, 0, 0, 0, 0, 0};
            avA[i] = zv; bvA[i] = zv;
            if (k0 + sk8 < K) {
                avA[i] = *reinterpret_cast<const short8*>(&A[(long)(m0 + r) * K + k0 + sk8]);
                if (n0 + r < N)
                    bvA[i] = *reinterpret_cast<const short8*>(&WT[(long)(n0 + r) * K + k0 + sk8]);
            }
        }
    };
    auto wrA = [&](int buf) {
        #pragma unroll
        for (int i = 0; i < 2; ++i) {
            const int r = sm + (i << 5);
            const int byte = (r << 7) + ((sk8 << 1) ^ ((r & 7) << 4));
            *reinterpret_cast<short8*>(reinterpret_cast<char*>(&As[buf][0]) + byte) = avA[i];
            *reinterpret_cast<short8*>(reinterpret_cast<char*>(&Bs[buf][0]) + byte) = bvA[i];
        }
    };
    auto domfma = [&](int buf) {
        #pragma unroll
        for (int kt = 0; kt < 2; ++kt) {
            const int kbyte = (kt << 6) + ((lane >> 4) << 4);
            const int ar = (w << 4) + (lane & 15);
            short8 a = *reinterpret_cast<const short8*>(
                reinterpret_cast<char*>(&As[buf][0]) + (ar << 7) + (kbyte ^ ((ar & 7) << 4)));
            #pragma unroll
            for (int nt = 0; nt < 4; ++nt) {
                const int br = (nt << 4) + (lane & 15);
                short8 bb = *reinterpret_cast<const short8*>(
                    reinterpret_cast<char*>(&Bs[buf][0]) + (br << 7) + (kbyte ^ ((br & 7) << 4)));
                acc[nt] = __builtin_amdgcn_mfma_f32_16x16x32_bf16(a, bb, acc[nt], 0, 0, 0);
            }
        }
    };

    loadA(0);
    wrA(0);
    if (nsteps > 1) loadA(64);
    __syncthreads();

    int cur = 0;
    for (int s = 0; s + 1 < nsteps; ++s) {
        domfma(cur);
        wrA(cur ^ 1);
        if (s + 2 < nsteps) loadA((s + 2) << 6);
        __syncthreads();
        cur ^= 1;
    }
    domfma(cur);

    if (MODE == 3) {
        // expert-head epilogue: pe[r][t] = sum over this block's cols of
        // relu(acc+bias) * hw2[z][col][t]; reduce over the 16 col-lanes.
        const int l15 = lane & 15, g = lane >> 4;
        float pe[4][2];
        #pragma unroll
        for (int r = 0; r < 4; ++r) { pe[r][0] = 0.f; pe[r][1] = 0.f; }
        #pragma unroll
        for (int nt = 0; nt < 4; ++nt) {
            const int c = n0 + (nt << 4) + l15;
            const float bv = bias[c];
            const float hw0 = x0[(((z << 8) + c) << 1) + 0];
            const float hw1 = x0[(((z << 8) + c) << 1) + 1];
            #pragma unroll
            for (int r = 0; r < 4; ++r) {
                float v = fmaxf(acc[nt][r] + bv, 0.f);
                pe[r][0] = fmaf(v, hw0, pe[r][0]);
                pe[r][1] = fmaf(v, hw1, pe[r][1]);
            }
        }
        #pragma unroll
        for (int r = 0; r < 4; ++r) {
            #pragma unroll
            for (int tt = 0; tt < 2; ++tt) {
                float v = pe[r][tt];
                v += __shfl_xor(v, 1); v += __shfl_xor(v, 2);
                v += __shfl_xor(v, 4); v += __shfl_xor(v, 8);
                pe[r][tt] = v;
            }
        }
        if (l15 == 0) {
            #pragma unroll
            for (int r = 0; r < 4; ++r) {
                const int row = m0 + (w << 4) + (g << 2) + r;
                const long o = (long)(((xb << 2) | z) * BB + row) << 1;
                outF[o + 0] = pe[r][0];
                outF[o + 1] = pe[r][1];
            }
        }
    } else {
        #pragma unroll
        for (int nt = 0; nt < 4; ++nt) {
            const int c = n0 + (nt << 4) + (lane & 15);
            if (c < N) {
                const float bv = bias[c];
                #pragma unroll
                for (int r = 0; r < 4; ++r) {
                    const int row = m0 + (w << 4) + ((lane >> 4) << 2) + r;
                    float v = acc[nt][r] + bv;
                    if (MODE == 1) v = fmaxf(v, 0.f);
                    const long o = (long)row * N + c;
                    if (MODE == 2) v = x0[o] * v + xin[o];
                    if (WF32) outF[oz + o] = v;
                    if (WB16) outB[oz + o] = f2b(v);
                }
            }
        }
    }
}

// ---------------------------------------------------------------------------
// LayerNorm over 392 (block per row), bf16 output only
// ---------------------------------------------------------------------------
__global__ __launch_bounds__(256) void ln_kernel(
    const float* __restrict__ in,
    const float* __restrict__ gamma, const float* __restrict__ beta,
    short* __restrict__ outB)
{
    __shared__ float red[2][4];
    __shared__ float stats[2];
    const int b = blockIdx.x, t = threadIdx.x, lane = t & 63, w = t >> 6;
    const long base = (long)b * DD;
    float v0 = in[base + t];
    float v1 = (t < 136) ? in[base + 256 + t] : 0.f;
    float s = v0 + v1, q2 = v0 * v0 + v1 * v1;
    #pragma unroll
    for (int off = 32; off > 0; off >>= 1) {
        s += __shfl_xor(s, off);
        q2 += __shfl_xor(q2, off);
    }
    if (lane == 0) { red[0][w] = s; red[1][w] = q2; }
    __syncthreads();
    if (t == 0) {
        float S = red[0][0] + red[0][1] + red[0][2] + red[0][3];
        float Q = red[1][0] + red[1][1] + red[1][2] + red[1][3];
        float mean = S / (float)DD;
        float var = Q / (float)DD - mean * mean;
        stats[0] = mean;
        stats[1] = rsqrtf(var + 1e-5f);
    }
    __syncthreads();
    const float mean = stats[0], inv = stats[1];
    outB[base + t] = f2b((v0 - mean) * inv * gamma[t] + beta[t]);
    if (t < 136)
        outB[base + 256 + t] = f2b((v1 - mean) * inv * gamma[256 + t] + beta[256 + t]);
}

// ---------------------------------------------------------------------------
// K3: gates (from x bf16, f32 math) + edPart sums + mix.
// ---------------------------------------------------------------------------
__global__ __launch_bounds__(256) void final_kernel(
    const short* __restrict__ x, const float* __restrict__ edPart,
    const float* __restrict__ hc,
    const float* __restrict__ gate_w, const float* __restrict__ gate_b,
    const float* __restrict__ head_b, float* __restrict__ out)
{
    const int t = threadIdx.x, lane = t & 63, w = t >> 6;
    const int b = blockIdx.x * 4 + w;
    const short* xr = x + (long)b * DD;

    float xv[7];
    #pragma unroll
    for (int i = 0; i < 7; ++i) {
        int d = lane + (i << 6);
        xv[i] = (d < DD) ? b2f(xr[d]) : 0.f;
    }

    float gl[8] = {0.f, 0.f, 0.f, 0.f, 0.f, 0.f, 0.f, 0.f};
    #pragma unroll
    for (int i = 0; i < 7; ++i) {
        int d = lane + (i << 6);
        if (d < DD) {
            float4 g0 = *reinterpret_cast<const float4*>(&gate_w[d << 2]);
            float4 g1 = *reinterpret_cast<const float4*>(&gate_w[1568 + (d << 2)]);
            gl[0] = fmaf(xv[i], g0.x, gl[0]); gl[1] = fmaf(xv[i], g0.y, gl[1]);
            gl[2] = fmaf(xv[i], g0.z, gl[2]); gl[3] = fmaf(xv[i], g0.w, gl[3]);
            gl[4] = fmaf(xv[i], g1.x, gl[4]); gl[5] = fmaf(xv[i], g1.y, gl[5]);
            gl[6] = fmaf(xv[i], g1.z, gl[6]); gl[7] = fmaf(xv[i], g1.w, gl[7]);
        }
    }

    #pragma unroll
    for (int v = 0; v < 8; ++v) {
        #pragma unroll
        for (int off = 32; off > 0; off >>= 1) gl[v] += __shfl_xor(gl[v], off);
    }

    // ed sums: lanes 0..7 each handle one (tt,e) pair
    float edv = 0.f;
    if (lane < 8) {
        const int tt = lane >> 2, e = lane & 3;
        #pragma unroll
        for (int nb = 0; nb < 4; ++nb)
            edv += edPart[((long)(((nb << 2) | e)) * BB + b) * 2 + tt];
    }
    float edArr[8];
    #pragma unroll
    for (int v = 0; v < 8; ++v) edArr[v] = __shfl(edv, v);

    if (lane == 0) {
        float res[2];
        #pragma unroll
        for (int tt = 0; tt < 2; ++tt) {
            float lv[4], m = -1e30f;
            #pragma unroll
            for (int e = 0; e < 4; ++e) {
                lv[e] = gl[tt * 4 + e] + gate_b[tt * 4 + e];
                m = fmaxf(m, lv[e]);
            }
            float sum = 0.f, acc = 0.f;
            #pragma unroll
            for (int e = 0; e < 4; ++e) { lv[e] = __expf(lv[e] - m); sum += lv[e]; }
            #pragma unroll
            for (int e = 0; e < 4; ++e)
                acc = fmaf(lv[e], edArr[tt * 4 + e] + hc[e * 2 + tt], acc);
            res[tt] = head_b[tt] + acc / sum;
        }
        out[b] = res[0];
        out[BB + b] = res[1];
    }
}

// ---------------------------------------------------------------------------
extern "C" void kernel_launch(void* const* d_in, const int* in_sizes, int n_in,
                              void* d_out, int out_size, void* d_ws, size_t ws_size,
                              hipStream_t stream) {
    const int*   userId    = (const int*)d_in[0];
    const int*   movieId   = (const int*)d_in[1];
    const int*   seq       = (const int*)d_in[2];
    const float* dense     = (const float*)d_in[3];
    const float* emb_user  = (const float*)d_in[4];
    const float* emb_movie = (const float*)d_in[5];
    const float* att_w1    = (const float*)d_in[6];
    const float* att_b1    = (const float*)d_in[7];
    const float* att_w2    = (const float*)d_in[8];
    const float* att_b2    = (const float*)d_in[9];
    const float* in_gamma  = (const float*)d_in[10];
    const float* in_beta   = (const float*)d_in[11];
    const float* cr_gamma  = (const float*)d_in[12];
    const float* cr_beta   = (const float*)d_in[13];
    const float* cross_W   = (const float*)d_in[14];
    const float* cross_b   = (const float*)d_in[15];
    const float* exp_w1    = (const float*)d_in[16];
    const float* exp_b1    = (const float*)d_in[17];
    const float* exp_w2    = (const float*)d_in[18];
    const float* exp_b2    = (const float*)d_in[19];
    const float* gate_w    = (const float*)d_in[20];
    const float* gate_b    = (const float*)d_in[21];
    const float* head_w    = (const float*)d_in[22];
    const float* head_b    = (const float*)d_in[23];
    float* outp = (float*)d_out;

    char* p = (char*)d_ws;
    auto alloc = [&](size_t bytes) -> char* {
        char* r = p; p += (bytes + 255) & ~(size_t)255; return r;
    };
    float* WkpFf = (float*)alloc(16384 * 4);
    float* hw2 = (float*)alloc(2048 * 4);
    float* hc  = (float*)alloc(8 * 4);
    short* WTc = (short*)alloc((size_t)3 * 392 * 392 * 2);
    short* WT1 = (short*)alloc((size_t)4 * 256 * 392 * 2);
    short* embB = (short*)alloc((size_t)50001 * 128 * 2);
    float* qcAll = (float*)alloc((size_t)BB * 64 * 4);
    float* x0f = (float*)alloc((size_t)BB * DD * 4);
    short* x0b = (short*)alloc((size_t)BB * DD * 2);
    float* xAf = (float*)alloc((size_t)BB * DD * 4);
    short* xAb = (short*)alloc((size_t)BB * DD * 2);
    float* xBf = (float*)alloc((size_t)BB * DD * 4);
    short* xBb = (short*)alloc((size_t)BB * DD * 2);
    float* xCf = (float*)alloc((size_t)BB * DD * 4);
    short* xDb = (short*)alloc((size_t)BB * DD * 2);
    float* edPart = (float*)alloc((size_t)16 * BB * 2 * 4);   // [nb*4+e][row][2]

    prep_all<<<NB_PREP, 256, 0, stream>>>(
        att_w1, exp_w2, exp_b2, head_w, att_b1, cross_W, exp_w1,
        emb_movie, movieId, WkpFf, hw2, hc, WTc, WT1, embB, qcAll);

    attn_kernel<<<BB, 256, 0, stream>>>(userId, movieId, seq, dense,
                                        emb_user, emb_movie, embB,
                                        qcAll, WkpFf, att_w2, att_b2,
                                        in_gamma, in_beta, x0f, x0b);

    // CrossNetV2: grid = 128 m-blocks * 7 n-blocks = 896 (%8==0)
    bgemm<2, 1, 1, 7, 1><<<896, 256, 0, stream>>>(x0b, WTc, cross_b, xAf, xAb,
                                                  x0f, x0f, BB, DD, DD, 0, 0, 0, 0);
    bgemm<2, 1, 1, 7, 1><<<896, 256, 0, stream>>>(xAb, WTc + 392 * 392, cross_b + 392,
                                                  xBf, xBb, x0f, xAf, BB, DD, DD, 0, 0, 0, 0);
    bgemm<2, 1, 0, 7, 1><<<896, 256, 0, stream>>>(xBb, WTc + 2 * 392 * 392, cross_b + 784,
                                                  xCf, nullptr, x0f, xBf, BB, DD, DD, 0, 0, 0, 0);

    // LN2: xCf -> xDb (bf16 only)
    ln_kernel<<<BB, 256, 0, stream>>>(xCf, cr_gamma, cr_beta, xDb);

    // Experts layer 1 fused with head dot: edPart (no h1 materialization)
    // grid = 128 m * 4 z * 4 xb = 2048 (%8==0)
    bgemm<3, 0, 0, 4, 4><<<2048, 256, 0, stream>>>(
        xDb, WT1, exp_b1, edPart, nullptr, hw2, nullptr,
        BB, HH1, DD, 0, (long)HH1 * DD, HH1, 0);

    // gates + edPart sums + mix -> logits [2][B]
    final_kernel<<<BB / 4, 256, 0, stream>>>(xDb, edPart, hc,
                                             gate_w, gate_b, head_b, outp);

    (void)in_sizes; (void)n_in; (void)out_size; (void)ws_size;
}